// Round 4
// baseline (399.860 us; speedup 1.0000x reference)
//
#include <hip/hip_runtime.h>

#define PBLK 256

typedef __attribute__((ext_vector_type(8))) short bf16x8;
typedef __attribute__((ext_vector_type(4))) float f32x4;

struct IPerm { int v[12]; };   // up to 3 perms x 4 atoms (inverse perms)

__device__ __forceinline__ unsigned short f2bf(float x) {
    unsigned int u = __builtin_bit_cast(unsigned int, x);
    u += 0x7fffu + ((u >> 16) & 1u);
    return (unsigned short)(u >> 16);
}

// ---- pre-pass 1: node_reps fp32 -> bf16 ----
__global__ void conv_node(const float* __restrict__ x, unsigned short* __restrict__ o, int n4) {
    int tid = blockIdx.x * PBLK + threadIdx.x;
    if (tid >= n4) return;
    const float4 v = reinterpret_cast<const float4*>(x)[tid];
    ushort4 r;
    r.x = f2bf(v.x); r.y = f2bf(v.y); r.z = f2bf(v.z); r.w = f2bf(v.w);
    reinterpret_cast<ushort4*>(o)[tid] = r;
}

// ---- pre-pass 2: pack w1 (K x 128 fp32) into per-perm B-fragment layout ----
// element order: (((ct*KT + kt)*64 + lane)*8 + j); lane -> col = ct*16+(l&15),
// k = kt*32 + (l>>4)*8 + j; source row permuted per inverse perm on 128-blocks.
template<int K>
__global__ void pack_w1(const float* __restrict__ w1, unsigned short* __restrict__ o,
                        int nperms, IPerm ip) {
    constexpr int KT = K / 32;
    const int per = K * 128;
    int tid = blockIdx.x * PBLK + threadIdx.x;
    if (tid >= nperms * per) return;
    const int p = tid / per;
    const int e = tid - p * per;
    const int j = e & 7;
    const int l = (e >> 3) & 63;
    const int ctkt = e >> 9;
    const int kt = ctkt % KT;
    const int ct = ctkt / KT;
    const int col = ct * 16 + (l & 15);
    const int k = kt * 32 + (l >> 4) * 8 + j;
    const int srow = ip.v[p * 4 + (k >> 7)] * 128 + (k & 127);
    o[tid] = f2bf(w1[(size_t)srow * 128 + col]);
}

// ---- async global->LDS, 16B per lane ----
__device__ __forceinline__ void gld_lds16(const unsigned short* g, unsigned char* l) {
    typedef __attribute__((address_space(1))) unsigned int GU;
    typedef __attribute__((address_space(3))) unsigned int LU;
    __builtin_amdgcn_global_load_lds((GU*)g, (LU*)l, 16, 0, 0);
}

template<int N> __device__ __forceinline__ void waitvm() {
    if constexpr (N == 0)      asm volatile("s_waitcnt vmcnt(0)" ::: "memory");
    else if constexpr (N == 2) asm volatile("s_waitcnt vmcnt(2)" ::: "memory");
    else                       asm volatile("s_waitcnt vmcnt(4)" ::: "memory");
}

// ---- main term kernel ----
// ROWS rows/block, 512 threads (8 waves = 2 row-groups x 4 col-groups).
// Wave computes (ROWS/2) rows x 32 cols. X staged per-atom via global_load_lds
// (pre-swizzled source, linear dest), double-buffered, 2 atoms in flight,
// counted vmcnt. Perms folded into packed W1 (X read once for all perms).
template<int NATOMS, int NPERMS, int DOUT, int ROWS>
__global__ __launch_bounds__(512, 4) void term_mfma(
    const unsigned short* __restrict__ nodeb,  // (N,128) bf16
    const int* __restrict__ idx,               // (nrows,NATOMS) or nullptr
    const unsigned short* __restrict__ pack,   // NPERMS * K * 128 bf16 packed
    const float* __restrict__ b1,              // (128)
    const float* __restrict__ w2,              // (128,DOUT)
    const float* __restrict__ b2,              // (DOUT)
    float* __restrict__ out,                   // (nrows,DOUT)
    int nrows)
{
    constexpr int KT   = NATOMS * 4;           // total k-tiles (K/32)
    constexpr int RT   = ROWS / 32;            // row tiles per wave
    constexpr int QG   = ROWS / 32;            // glds instrs per wave per atom
    constexpr int RPW  = ROWS / 8;             // staging rows per wave
    constexpr int ABUF = ROWS * 256;           // bytes per atom buffer
    __shared__ __align__(16) unsigned char lds[2 * ABUF];   // == ROWS*128*4 for h

    const int t  = threadIdx.x;
    const int l  = t & 63;
    const int w  = t >> 6;
    const int lm = l & 15;
    const int hi = l >> 4;
    const int rg = w >> 2;                     // row group (0..1)
    const int cg = w & 3;                      // col group (0..3)
    const int r0 = blockIdx.x * ROWS;

    // stage atom a into buffer bsel: linear LDS dest, inverse-swizzled source
    auto stage = [&](int a, int bsel) {
        unsigned char* buf = lds + bsel * ABUF;
        const int rb = w * RPW;
        #pragma unroll
        for (int q = 0; q < QG; ++q) {
            const int rl = rb + q * 4 + (l >> 4);
            int rgl = r0 + rl; if (rgl >= nrows) rgl = nrows - 1;
            const int nrow = idx ? idx[rgl * NATOMS + a] : rgl;
            const unsigned short* src = nodeb + (size_t)nrow * 128 + ((lm ^ (rl & 15)) << 3);
            gld_lds16(src, buf + (rb + q * 4) * 256);
        }
    };

    const int col0 = cg * 32 + lm;
    const float bv0 = b1[col0];
    const float bv1 = b1[col0 + 16];
    f32x4 acc[NPERMS][RT][2];
    #pragma unroll
    for (int p = 0; p < NPERMS; ++p)
        #pragma unroll
        for (int rt = 0; rt < RT; ++rt) {
            acc[p][rt][0] = (f32x4){bv0, bv0, bv0, bv0};
            acc[p][rt][1] = (f32x4){bv1, bv1, bv1, bv1};
        }

    stage(0, 0);
    if (NATOMS > 1) stage(1, 1);

    #pragma unroll
    for (int a = 0; a < NATOMS; ++a) {
        if (a == NATOMS - 1) waitvm<0>(); else waitvm<QG>();
        __syncthreads();
        const unsigned char* xb = lds + (a & 1) * ABUF;
        #pragma unroll
        for (int ktl = 0; ktl < 4; ++ktl) {
            const int kt = a * 4 + ktl;
            bf16x8 av[RT];
            #pragma unroll
            for (int rt = 0; rt < RT; ++rt) {
                const int row = rg * (ROWS / 2) + rt * 16 + lm;
                av[rt] = *reinterpret_cast<const bf16x8*>(
                    xb + row * 256 + (((ktl * 4 + hi) ^ (row & 15)) << 4));
            }
            #pragma unroll
            for (int p = 0; p < NPERMS; ++p) {
                #pragma unroll
                for (int ct = 0; ct < 2; ++ct) {
                    const int ctg = cg * 2 + ct;
                    const bf16x8 bf = *reinterpret_cast<const bf16x8*>(
                        pack + (size_t)p * KT * 32 * 128 + ((size_t)(ctg * KT + kt) * 64 + l) * 8);
                    #pragma unroll
                    for (int rt = 0; rt < RT; ++rt)
                        acc[p][rt][ct] = __builtin_amdgcn_mfma_f32_16x16x32_bf16(av[rt], bf, acc[p][rt][ct], 0, 0, 0);
                }
            }
        }
        __syncthreads();
        if (a + 2 < NATOMS) stage(a + 2, a & 1);
    }

    // ---- stage h = sum_p relu(acc_p) into LDS (fp32, swizzled) ----
    float* hs = reinterpret_cast<float*>(lds);
    #pragma unroll
    for (int rt = 0; rt < RT; ++rt) {
        #pragma unroll
        for (int i = 0; i < 4; ++i) {
            const int row = rg * (ROWS / 2) + rt * 16 + hi * 4 + i;
            #pragma unroll
            for (int ct = 0; ct < 2; ++ct) {
                float v = 0.0f;
                #pragma unroll
                for (int p = 0; p < NPERMS; ++p) v += fmaxf(acc[p][rt][ct][i], 0.0f);
                hs[row * 128 + ((col0 + ct * 16) ^ ((row & 7) << 2))] = v;
            }
        }
    }
    __syncthreads();

    // ---- layer 2: y = h @ w2 + NPERMS*b2 ----
    for (int q = t; q < ROWS * DOUT; q += 512) {
        const int r = q / DOUT;
        const int o = q - r * DOUT;
        float y0 = 0.f, y1 = 0.f, y2 = 0.f, y3 = 0.f;
        #pragma unroll 4
        for (int c = 0; c < 128; c += 4) {
            y0 += hs[r * 128 + ((c    ) ^ ((r & 7) << 2))] * w2[(size_t)(c    ) * DOUT + o];
            y1 += hs[r * 128 + ((c + 1) ^ ((r & 7) << 2))] * w2[(size_t)(c + 1) * DOUT + o];
            y2 += hs[r * 128 + ((c + 2) ^ ((r & 7) << 2))] * w2[(size_t)(c + 2) * DOUT + o];
            y3 += hs[r * 128 + ((c + 3) ^ ((r & 7) << 2))] * w2[(size_t)(c + 3) * DOUT + o];
        }
        const float y = b2[o] * (float)NPERMS + ((y0 + y1) + (y2 + y3));
        const int row = r0 + r;
        if (row < nrows) out[(size_t)row * DOUT + o] = y;
    }
}

extern "C" void kernel_launch(void* const* d_in, const int* in_sizes, int n_in,
                              void* d_out, int out_size, void* d_ws, size_t ws_size,
                              hipStream_t stream) {
    const float* node = (const float*)d_in[0];
    const int* bidx = (const int*)d_in[1];
    const int* gidx = (const int*)d_in[2];
    const int* pidx = (const int*)d_in[3];
    const int* iidx = (const int*)d_in[4];

    const float* aw1 = (const float*)d_in[5];
    const float* ab1 = (const float*)d_in[6];
    const float* aw2 = (const float*)d_in[7];
    const float* ab2 = (const float*)d_in[8];
    const float* bw1 = (const float*)d_in[9];
    const float* bb1 = (const float*)d_in[10];
    const float* bw2 = (const float*)d_in[11];
    const float* bb2 = (const float*)d_in[12];
    const float* gw1 = (const float*)d_in[13];
    const float* gb1 = (const float*)d_in[14];
    const float* gw2 = (const float*)d_in[15];
    const float* gb2 = (const float*)d_in[16];
    const float* pw1 = (const float*)d_in[17];
    const float* pb1 = (const float*)d_in[18];
    const float* pw2 = (const float*)d_in[19];
    const float* pb2 = (const float*)d_in[20];
    const float* iw1 = (const float*)d_in[21];
    const float* ib1 = (const float*)d_in[22];
    const float* iw2 = (const float*)d_in[23];
    const float* ib2 = (const float*)d_in[24];

    const int N  = in_sizes[0] / 128;
    const int NB = in_sizes[1] / 2;
    const int NA = in_sizes[2] / 3;
    const int NP = in_sizes[3] / 4;
    const int NI = in_sizes[4] / 4;

    float* out   = (float*)d_out;
    float* out_a = out;
    float* out_b = out_a + (size_t)N  * 2;
    float* out_g = out_b + (size_t)NB * 2;
    float* out_p = out_g + (size_t)NA * 2;
    float* out_i = out_p + (size_t)NP * 6;

    // ---- workspace layout (bf16 elements) ----
    unsigned short* nodeb = (unsigned short*)d_ws;
    size_t off = (size_t)N * 128;
    unsigned short* packA = nodeb + off; off += (size_t)1 * 128 * 128;
    unsigned short* packB = nodeb + off; off += (size_t)2 * 256 * 128;
    unsigned short* packG = nodeb + off; off += (size_t)2 * 384 * 128;
    unsigned short* packP = nodeb + off; off += (size_t)2 * 512 * 128;
    unsigned short* packI = nodeb + off; off += (size_t)3 * 512 * 128;

    // ---- pre-pass: convert node, pack weights ----
    {
        const int n4 = N * 128 / 4;
        conv_node<<<(n4 + PBLK - 1) / PBLK, PBLK, 0, stream>>>(node, nodeb, n4);
    }
    IPerm ipa{{0,0,0,0,  0,0,0,0,  0,0,0,0}};
    IPerm ipb{{0,1,0,0,  1,0,0,0,  0,0,0,0}};
    IPerm ipg{{0,1,2,0,  2,1,0,0,  0,0,0,0}};
    IPerm ipp{{0,1,2,3,  3,2,1,0,  0,0,0,0}};
    IPerm ipi{{0,1,2,3,  3,1,0,2,  2,1,3,0}};   // inverses of (0123),(2130),(3102)

    pack_w1<128><<<(1 * 128 * 128 + PBLK - 1) / PBLK, PBLK, 0, stream>>>(aw1, packA, 1, ipa);
    pack_w1<256><<<(2 * 256 * 128 + PBLK - 1) / PBLK, PBLK, 0, stream>>>(bw1, packB, 2, ipb);
    pack_w1<384><<<(2 * 384 * 128 + PBLK - 1) / PBLK, PBLK, 0, stream>>>(gw1, packG, 2, ipg);
    pack_w1<512><<<(2 * 512 * 128 + PBLK - 1) / PBLK, PBLK, 0, stream>>>(pw1, packP, 2, ipp);
    pack_w1<512><<<(3 * 512 * 128 + PBLK - 1) / PBLK, PBLK, 0, stream>>>(iw1, packI, 3, ipi);

    // ---- term kernels ----
    term_mfma<1, 1, 2, 128><<<(N  + 127) / 128, 512, 0, stream>>>(nodeb, nullptr, packA, ab1, aw2, ab2, out_a, N);
    term_mfma<2, 2, 2, 128><<<(NB + 127) / 128, 512, 0, stream>>>(nodeb, bidx,    packB, bb1, bw2, bb2, out_b, NB);
    term_mfma<3, 2, 2, 128><<<(NA + 127) / 128, 512, 0, stream>>>(nodeb, gidx,    packG, gb1, gw2, gb2, out_g, NA);
    term_mfma<4, 2, 6, 128><<<(NP + 127) / 128, 512, 0, stream>>>(nodeb, pidx,    packP, pb1, pw2, pb2, out_p, NP);
    term_mfma<4, 3, 6,  64><<<(NI +  63) /  64, 512, 0, stream>>>(nodeb, iidx,    packI, ib1, iw2, ib2, out_i, NI);
}

// Round 5
// 341.655 us; speedup vs baseline: 1.1704x; 1.1704x over previous
//
#include <hip/hip_runtime.h>

#define PBLK 256

typedef __attribute__((ext_vector_type(8))) short bf16x8;
typedef __attribute__((ext_vector_type(16))) float f32x16;

struct IPerm { int v[12]; };   // up to 3 perms x 4 atoms (inverse perms)

__device__ __forceinline__ unsigned short f2bf(float x) {
    unsigned int u = __builtin_bit_cast(unsigned int, x);
    u += 0x7fffu + ((u >> 16) & 1u);
    return (unsigned short)(u >> 16);
}

// ---- pre-pass 1: node_reps fp32 -> bf16 ----
__global__ void conv_node(const float* __restrict__ x, unsigned short* __restrict__ o, int n4) {
    int tid = blockIdx.x * PBLK + threadIdx.x;
    if (tid >= n4) return;
    const float4 v = reinterpret_cast<const float4*>(x)[tid];
    ushort4 r;
    r.x = f2bf(v.x); r.y = f2bf(v.y); r.z = f2bf(v.z); r.w = f2bf(v.w);
    reinterpret_cast<ushort4*>(o)[tid] = r;
}

// ---- pre-pass 2: pack w1 into per-perm 32x32x16 B-fragment layout ----
// o[(((p*4+ct)*KS + s)*64 + l)*8 + j]; lane l -> col = ct*32+(l&31),
// k = s*16 + (l>>5)*8 + j; source row permuted per inverse perm on 128-blocks.
template<int K>
__global__ void pack_w1(const float* __restrict__ w1, unsigned short* __restrict__ o,
                        int nperms, IPerm ip) {
    constexpr int KS = K / 16;
    const int per = K * 128;
    int tid = blockIdx.x * PBLK + threadIdx.x;
    if (tid >= nperms * per) return;
    const int p = tid / per;
    const int e = tid - p * per;
    const int j = e & 7;
    const int l = (e >> 3) & 63;
    const int cts = e >> 9;            // ct*KS + s
    const int s  = cts % KS;
    const int ct = cts / KS;
    const int col = ct * 32 + (l & 31);
    const int k = s * 16 + (l >> 5) * 8 + j;
    const int srow = ip.v[p * 4 + (k >> 7)] * 128 + (k & 127);
    o[tid] = f2bf(w1[(size_t)srow * 128 + col]);
}

// ---- async global->LDS, 16B per lane ----
__device__ __forceinline__ void gld_lds16(const unsigned short* g, unsigned char* l) {
    typedef __attribute__((address_space(1))) unsigned int GU;
    typedef __attribute__((address_space(3))) unsigned int LU;
    __builtin_amdgcn_global_load_lds((GU*)g, (LU*)l, 16, 0, 0);
}

template<int N> __device__ __forceinline__ void waitvm() {
    if constexpr (N == 0)       asm volatile("s_waitcnt vmcnt(0)" ::: "memory");
    else if constexpr (N == 2)  asm volatile("s_waitcnt vmcnt(2)" ::: "memory");
    else if constexpr (N == 16) asm volatile("s_waitcnt vmcnt(16)" ::: "memory");
    else                        asm volatile("s_waitcnt vmcnt(18)" ::: "memory");
}

// raw barrier (no implicit vmcnt(0) drain — keeps prefetched glds in flight)
__device__ __forceinline__ void bar() {
    asm volatile("" ::: "memory");
    __builtin_amdgcn_s_barrier();
    asm volatile("" ::: "memory");
}

// ---- main term kernel ----
// ROWS=64 rows/block, 512 threads = 8 waves (2 row-grp x 4 col-grp), wave tile
// 32 rows x 32 cols, mfma_f32_32x32x16_bf16, NPERMS accumulators in AGPRs.
// X staged per-atom via global_load_lds (16KB double-buffer, counted vmcnt,
// raw barriers). All B frags of an atom batch-loaded into a register array.
template<int NATOMS, int NPERMS, int DOUT, int MINW>
__global__ __launch_bounds__(512, MINW) void term_mfma(
    const unsigned short* __restrict__ nodeb,  // (N,128) bf16
    const int* __restrict__ idx,               // (nrows,NATOMS) or nullptr
    const unsigned short* __restrict__ pack,   // NPERMS*K*128 bf16 packed
    const float* __restrict__ b1,              // (128)
    const float* __restrict__ w2,              // (128,DOUT)
    const float* __restrict__ b2,              // (DOUT)
    float* __restrict__ out,                   // (nrows,DOUT)
    int nrows)
{
    constexpr int ROWS = 64;
    constexpr int KS   = NATOMS * 8;           // total k-steps of 16
    constexpr int ABUF = ROWS * 256;           // 16KB per atom buffer
    __shared__ __align__(16) unsigned char lds[2 * ABUF];   // 32KB (h reuses all)

    const int t    = threadIdx.x;
    const int l    = t & 63;
    const int w    = t >> 6;
    const int hi32 = l >> 5;
    const int l31  = l & 31;
    const int rg   = w >> 2;
    const int cg   = w & 3;
    const int r0   = blockIdx.x * ROWS;
    const int rb   = w * 8;

    // prefetch gather indices into registers (glds addresses never stall)
    int nrow_r[NATOMS * 2];
    #pragma unroll
    for (int a = 0; a < NATOMS; ++a)
        #pragma unroll
        for (int q = 0; q < 2; ++q) {
            const int rl = rb + q * 4 + (l >> 4);
            int row = r0 + rl; if (row >= nrows) row = nrows - 1;
            nrow_r[a * 2 + q] = idx ? idx[row * NATOMS + a] : row;
        }

#define STAGE(A, BSEL) do {                                                          \
    unsigned char* buf_ = lds + (BSEL) * ABUF;                                       \
    _Pragma("unroll")                                                                \
    for (int q_ = 0; q_ < 2; ++q_) {                                                 \
        const int rl_ = rb + q_ * 4 + (l >> 4);                                      \
        const unsigned short* src_ = nodeb + (size_t)nrow_r[(A) * 2 + q_] * 128      \
                                     + (((l & 15) ^ (rl_ & 15)) << 3);               \
        gld_lds16(src_, buf_ + (rb + q_ * 4) * 256);                                 \
    } } while (0)

    const int col = cg * 32 + l31;
    const float bv = b1[col];
    f32x16 acc[NPERMS];
    #pragma unroll
    for (int p = 0; p < NPERMS; ++p)
        #pragma unroll
        for (int i = 0; i < 16; ++i) acc[p][i] = bv;

    STAGE(0, 0);
    if (NATOMS > 1) STAGE(1, 1);

    #pragma unroll
    for (int a = 0; a < NATOMS; ++a) {
        // wait until this atom's glds are complete (keep newer ops in flight)
        if (a == 0)                { if (NATOMS > 1) waitvm<2>(); else waitvm<0>(); }
        else if (a + 1 < NATOMS)   waitvm<18>();
        else                       waitvm<16>();
        bar();

        // batch-load ALL B fragments of this atom (independent -> one latency)
        bf16x8 B[NPERMS * 8];
        #pragma unroll
        for (int p = 0; p < NPERMS; ++p)
            #pragma unroll
            for (int s = 0; s < 8; ++s)
                B[p * 8 + s] = *reinterpret_cast<const bf16x8*>(
                    pack + (((size_t)(p * 4 + cg) * KS + (a * 8 + s)) * 64 + l) * 8);

        const unsigned char* xb = lds + (a & 1) * ABUF;
        const int rowb = rg * 32 + l31;
        #pragma unroll
        for (int s = 0; s < 8; ++s) {
            const bf16x8 av = *reinterpret_cast<const bf16x8*>(
                xb + rowb * 256 + (((s * 2 + hi32) ^ (l & 15)) << 4));
            #pragma unroll
            for (int p = 0; p < NPERMS; ++p)
                acc[p] = __builtin_amdgcn_mfma_f32_32x32x16_bf16(av, B[p * 8 + s], acc[p], 0, 0, 0);
        }
        asm volatile("s_waitcnt lgkmcnt(0)" ::: "memory");   // ds_reads retired
        bar();
        if (a + 2 < NATOMS) STAGE(a + 2, a & 1);             // overwrite freed buffer
    }
#undef STAGE

    // ---- h = sum_p relu(acc_p) -> LDS (fp32, swizzled); C layout per m74/m101 ----
    float* hs = reinterpret_cast<float*>(lds);
    #pragma unroll
    for (int i = 0; i < 16; ++i) {
        const int rowl = rg * 32 + (i & 3) + 8 * (i >> 2) + 4 * hi32;
        float v = 0.0f;
        #pragma unroll
        for (int p = 0; p < NPERMS; ++p) v += fmaxf(acc[p][i], 0.0f);
        hs[rowl * 128 + (col ^ ((rowl & 7) << 2))] = v;
    }
    __syncthreads();

    // ---- layer 2: y = h @ w2 + NPERMS*b2 ----
    if (t < ROWS * DOUT) {
        const int r = t / DOUT;
        const int o = t - r * DOUT;
        float y0 = 0.f, y1 = 0.f, y2 = 0.f, y3 = 0.f;
        #pragma unroll 4
        for (int c = 0; c < 128; c += 4) {
            y0 += hs[r * 128 + ((c    ) ^ ((r & 7) << 2))] * w2[(size_t)(c    ) * DOUT + o];
            y1 += hs[r * 128 + ((c + 1) ^ ((r & 7) << 2))] * w2[(size_t)(c + 1) * DOUT + o];
            y2 += hs[r * 128 + ((c + 2) ^ ((r & 7) << 2))] * w2[(size_t)(c + 2) * DOUT + o];
            y3 += hs[r * 128 + ((c + 3) ^ ((r & 7) << 2))] * w2[(size_t)(c + 3) * DOUT + o];
        }
        const float y = b2[o] * (float)NPERMS + ((y0 + y1) + (y2 + y3));
        const int row = r0 + r;
        if (row < nrows) out[(size_t)row * DOUT + o] = y;
    }
}

extern "C" void kernel_launch(void* const* d_in, const int* in_sizes, int n_in,
                              void* d_out, int out_size, void* d_ws, size_t ws_size,
                              hipStream_t stream) {
    const float* node = (const float*)d_in[0];
    const int* bidx = (const int*)d_in[1];
    const int* gidx = (const int*)d_in[2];
    const int* pidx = (const int*)d_in[3];
    const int* iidx = (const int*)d_in[4];

    const float* aw1 = (const float*)d_in[5];
    const float* ab1 = (const float*)d_in[6];
    const float* aw2 = (const float*)d_in[7];
    const float* ab2 = (const float*)d_in[8];
    const float* bw1 = (const float*)d_in[9];
    const float* bb1 = (const float*)d_in[10];
    const float* bw2 = (const float*)d_in[11];
    const float* bb2 = (const float*)d_in[12];
    const float* gw1 = (const float*)d_in[13];
    const float* gb1 = (const float*)d_in[14];
    const float* gw2 = (const float*)d_in[15];
    const float* gb2 = (const float*)d_in[16];
    const float* pw1 = (const float*)d_in[17];
    const float* pb1 = (const float*)d_in[18];
    const float* pw2 = (const float*)d_in[19];
    const float* pb2 = (const float*)d_in[20];
    const float* iw1 = (const float*)d_in[21];
    const float* ib1 = (const float*)d_in[22];
    const float* iw2 = (const float*)d_in[23];
    const float* ib2 = (const float*)d_in[24];

    const int N  = in_sizes[0] / 128;
    const int NB = in_sizes[1] / 2;
    const int NA = in_sizes[2] / 3;
    const int NP = in_sizes[3] / 4;
    const int NI = in_sizes[4] / 4;

    float* out   = (float*)d_out;
    float* out_a = out;
    float* out_b = out_a + (size_t)N  * 2;
    float* out_g = out_b + (size_t)NB * 2;
    float* out_p = out_g + (size_t)NA * 2;
    float* out_i = out_p + (size_t)NP * 6;

    // ---- workspace layout (bf16 elements) ----
    unsigned short* nodeb = (unsigned short*)d_ws;
    size_t off = (size_t)N * 128;
    unsigned short* packA = nodeb + off; off += (size_t)1 * 128 * 128;
    unsigned short* packB = nodeb + off; off += (size_t)2 * 256 * 128;
    unsigned short* packG = nodeb + off; off += (size_t)2 * 384 * 128;
    unsigned short* packP = nodeb + off; off += (size_t)2 * 512 * 128;
    unsigned short* packI = nodeb + off; off += (size_t)3 * 512 * 128;

    // ---- pre-pass: convert node, pack weights ----
    {
        const int n4 = N * 128 / 4;
        conv_node<<<(n4 + PBLK - 1) / PBLK, PBLK, 0, stream>>>(node, nodeb, n4);
    }
    IPerm ipa{{0,0,0,0,  0,0,0,0,  0,0,0,0}};
    IPerm ipb{{0,1,0,0,  1,0,0,0,  0,0,0,0}};
    IPerm ipg{{0,1,2,0,  2,1,0,0,  0,0,0,0}};
    IPerm ipp{{0,1,2,3,  3,2,1,0,  0,0,0,0}};
    IPerm ipi{{0,1,2,3,  3,1,0,2,  2,1,3,0}};   // inverses of (0123),(2130),(3102)

    pack_w1<128><<<(1 * 128 * 128 + PBLK - 1) / PBLK, PBLK, 0, stream>>>(aw1, packA, 1, ipa);
    pack_w1<256><<<(2 * 256 * 128 + PBLK - 1) / PBLK, PBLK, 0, stream>>>(bw1, packB, 2, ipb);
    pack_w1<384><<<(2 * 384 * 128 + PBLK - 1) / PBLK, PBLK, 0, stream>>>(gw1, packG, 2, ipg);
    pack_w1<512><<<(2 * 512 * 128 + PBLK - 1) / PBLK, PBLK, 0, stream>>>(pw1, packP, 2, ipp);
    pack_w1<512><<<(3 * 512 * 128 + PBLK - 1) / PBLK, PBLK, 0, stream>>>(iw1, packI, 3, ipi);

    // ---- term kernels ----
    term_mfma<1, 1, 2, 4><<<(N  + 63) / 64, 512, 0, stream>>>(nodeb, nullptr, packA, ab1, aw2, ab2, out_a, N);
    term_mfma<2, 2, 2, 4><<<(NB + 63) / 64, 512, 0, stream>>>(nodeb, bidx,    packB, bb1, bw2, bb2, out_b, NB);
    term_mfma<3, 2, 2, 4><<<(NA + 63) / 64, 512, 0, stream>>>(nodeb, gidx,    packG, gb1, gw2, gb2, out_g, NA);
    term_mfma<4, 2, 6, 4><<<(NP + 63) / 64, 512, 0, stream>>>(nodeb, pidx,    packP, pb1, pw2, pb2, out_p, NP);
    term_mfma<4, 3, 6, 2><<<(NI + 63) / 64, 512, 0, stream>>>(nodeb, iidx,    packI, ib1, iw2, ib2, out_i, NI);
}